// Round 17
// baseline (142.557 us; speedup 1.0000x reference)
//
#include <hip/hip_runtime.h>
#include <stdint.h>

#define NROWS 16384
#define DIM 64
#define BK 64
#define NT (NROWS / BK)        // 256 KV tiles
#define NQB (NROWS / 128)      // 128 q-blocks (128 q-rows each)
#define TILE_BYTES 16384       // K f16 (8K) + Vt bf16 (8K, k-permuted), swizzled
#define VT_OFF 8192
#define LOG2E 1.4426950408889634f
#define MHAT_COEF 20.0f

typedef __attribute__((ext_vector_type(8))) _Float16 f16x8;
typedef __attribute__((ext_vector_type(8))) unsigned short ushort8;
typedef __attribute__((ext_vector_type(4))) float f32x4;
typedef __attribute__((ext_vector_type(8))) __bf16 bf16x8;
typedef __attribute__((ext_vector_type(8))) short short8;

static __device__ __forceinline__ f32x4 mfma_f16(f16x8 a, f16x8 b, f32x4 c) {
  return __builtin_amdgcn_mfma_f32_16x16x32_f16(a, b, c, 0, 0, 0);
}
static __device__ __forceinline__ f32x4 mfma_bf16(short8 a, short8 b, f32x4 c) {
  return __builtin_amdgcn_mfma_f32_16x16x32_bf16(
      __builtin_bit_cast(bf16x8, a), __builtin_bit_cast(bf16x8, b), c, 0, 0, 0);
}
static __device__ __forceinline__ void gload_lds16(const void* g, void* l) {
  __builtin_amdgcn_global_load_lds(
      (const __attribute__((address_space(1))) unsigned int*)(uintptr_t)g,
      (__attribute__((address_space(3))) unsigned int*)(unsigned int)(uintptr_t)l,
      16, 0, 0);
}
static __device__ __forceinline__ float fast_exp2(float x) {
  return __builtin_amdgcn_exp2f(x);   // single v_exp_f32, hazard-scheduled
}
static __device__ __forceinline__ unsigned short f2bfbits(float x) {
  return __builtin_bit_cast(unsigned short, (__bf16)x);  // compiler emits cvt
}
// scalar bf16 helpers (pack + fallback)
static __device__ __forceinline__ unsigned short f2bf(float x) {
  unsigned u = __builtin_bit_cast(unsigned, x);
  u = (u + 0x7fffu + ((u >> 16) & 1u)) >> 16;
  return (unsigned short)u;
}
static __device__ __forceinline__ float bf2f(unsigned short b) {
  return __builtin_bit_cast(float, ((unsigned)b) << 16);
}

// ---------------- prologue: pack p -> swizzled tiles + row offsets ----------
// K half (f16): rows as-is. Vt half (bf16): vt[d][pos] = V[pi(pos)][d] with
// pi(chunk*32 + lg*8 + i) = chunk*32 + (i/4)*16 + lg*4 + (i%4)  (zero-shuffle PV).
// mhat[row] = MHAT_COEF * ||p_row|| * LOG2E  (fixed log2-domain softmax offset).
__global__ __launch_bounds__(256)
void pack_kernel(const float* __restrict__ p, unsigned char* __restrict__ tiles,
                 float* __restrict__ mhat) {
  __shared__ unsigned short sT[64][68];
  const int kt = blockIdx.x;
  const int t  = threadIdx.x;
  const int r  = t >> 2;
  const int q4 = t & 3;
  const int d0 = q4 * 16;

  const float* src = p + ((size_t)(kt * 64 + r)) * DIM + d0;
  float4 f0 = ((const float4*)src)[0];
  float4 f1 = ((const float4*)src)[1];
  float4 f2 = ((const float4*)src)[2];
  float4 f3 = ((const float4*)src)[3];
  float v[16] = {f0.x, f0.y, f0.z, f0.w, f1.x, f1.y, f1.z, f1.w,
                 f2.x, f2.y, f2.z, f2.w, f3.x, f3.y, f3.z, f3.w};
  ushort8 h0, h1, hb0, hb1;
  float sq = 0.f;
#pragma unroll
  for (int i = 0; i < 8; ++i) {
    h0[i]  = __builtin_bit_cast(unsigned short, (_Float16)v[i]);      // f16 RNE
    h1[i]  = __builtin_bit_cast(unsigned short, (_Float16)v[8 + i]);
    hb0[i] = f2bf(v[i]);                                              // bf16 RNE
    hb1[i] = f2bf(v[8 + i]);
    sq = fmaf(v[i], v[i], sq);
    sq = fmaf(v[8 + i], v[8 + i], sq);
  }
  unsigned char* tb = tiles + (size_t)kt * TILE_BYTES;
  const int swz = (r & 7) << 4;
  *(ushort8*)(tb + r * 128 + ((2 * d0) ^ swz))      = h0;
  *(ushort8*)(tb + r * 128 + ((2 * d0 + 16) ^ swz)) = h1;

  // fixed softmax offset
  sq += __shfl_xor(sq, 1);
  sq += __shfl_xor(sq, 2);
  if (q4 == 0) mhat[kt * 64 + r] = MHAT_COEF * LOG2E * sqrtf(sq);

  // Vt (bf16) via LDS transpose, pi-permuted rows
  *(ushort8*)&sT[r][d0]     = hb0;
  *(ushort8*)&sT[r][d0 + 8] = hb1;
  __syncthreads();
  const int d    = t >> 2;
  const int base = (q4 >> 1) * 32 + (q4 & 1) * 8;   // pi-gather base
  ushort8 a8, b8;
#pragma unroll
  for (int j = 0; j < 8; ++j) {
    a8[j] = sT[base + (j >> 2) * 16 + (j & 3)][d];      // pos q4*16 + j
    b8[j] = sT[base + (j >> 2) * 16 + 4 + (j & 3)][d];  // pos q4*16 + 8 + j
  }
  const int swzd = (d & 7) << 4;
  *(ushort8*)(tb + VT_OFF + d * 128 + ((2 * (q4 * 16)) ^ swzd))      = a8;
  *(ushort8*)(tb + VT_OFF + d * 128 + ((2 * (q4 * 16) + 16) ^ swzd)) = b8;
}

// ------- main flash kernel: 128 q/block, 32 q/wave; K via LDS, Vt via L1 ----
__global__ __launch_bounds__(256)
void attn_main(const float* __restrict__ p, const unsigned char* __restrict__ tiles,
               const float* __restrict__ mhat, float* __restrict__ out,
               float* __restrict__ partO, float* __restrict__ partL,
               int S, int writeDirect) {
  __shared__ __align__(16) unsigned char sbuf[2][8192];   // K halves only, 16 KB

  const int t  = threadIdx.x;
  const int w  = t >> 6;
  const int l  = t & 63;
  const int lr = l & 15;
  const int lg = l >> 4;
  const int qt = blockIdx.x;          // 0..NQB-1 (128 q-rows)
  const int s  = blockIdx.y;
  const int ntp = NT / S;
  const int kt0 = s * ntp;
  const int swz = (lr & 7) << 4;
  const int ko0 = (lg * 16) ^ swz;
  const int ko1 = (64 + lg * 16) ^ swz;

  // Q fragments for two 16-row groups: q = qt*128 + w*32 + g*16 + lr
  f16x8 qf[2][2];
  float nm[2];
#pragma unroll
  for (int g = 0; g < 2; ++g) {
    const int grow = w * 32 + g * 16;
    const unsigned char* qtb =
        tiles + (size_t)(qt * 2 + (grow >> 6)) * TILE_BYTES;
    const int rin = (grow & 63) + lr;
    qf[g][0] = *(const f16x8*)(qtb + rin * 128 + ko0);
    qf[g][1] = *(const f16x8*)(qtb + rin * 128 + ko1);
    nm[g] = -mhat[qt * 128 + grow + lr];
  }

  const f32x4 z4 = {0.f, 0.f, 0.f, 0.f};
  f32x4 oacc[2][4] = {{z4, z4, z4, z4}, {z4, z4, z4, z4}};
  float lrun[2] = {0.f, 0.f};        // per-lane partial denominators
  const float S2 = -4.0f * LOG2E;

  // stage K half (8KB) of tile kt into buffer b: 2KB per wave
  auto STAGE = [&](int kt, int b) {
    const unsigned char* g = tiles + (size_t)kt * TILE_BYTES + (w * 2) * 1024 + l * 16;
    unsigned char* lb = &sbuf[b][(w * 2) * 1024];   // wave-uniform LDS base
#pragma unroll
    for (int c = 0; c < 2; ++c)
      gload_lds16(g + c * 1024, lb + c * 1024);
  };

  STAGE(kt0, 0);
  __syncthreads();

  for (int i = 0; i < ntp; ++i) {
    if (i + 1 < ntp) STAGE(kt0 + i + 1, (i + 1) & 1);

    const unsigned char* kb  = &sbuf[i & 1][0];
    const unsigned char* vtg = tiles + (size_t)(kt0 + i) * TILE_BYTES + VT_OFF;

    // ---- QK^T swapped: each kf (LDS) feeds both q-groups
    f32x4 acc[2][4] = {{z4, z4, z4, z4}, {z4, z4, z4, z4}};
#pragma unroll
    for (int c = 0; c < 4; ++c) {
      f16x8 kf0 = *(const f16x8*)(kb + (c * 16 + lr) * 128 + ko0);
      f16x8 kf1 = *(const f16x8*)(kb + (c * 16 + lr) * 128 + ko1);
      acc[0][c] = mfma_f16(kf0, qf[0][0], acc[0][c]);
      acc[1][c] = mfma_f16(kf0, qf[1][0], acc[1][c]);
      acc[0][c] = mfma_f16(kf1, qf[0][1], acc[0][c]);
      acc[1][c] = mfma_f16(kf1, qf[1][1], acc[1][c]);
    }

    // ---- fixed-m softmax per group: P = 2^(S2*dot - mhat); no shfl, no branch
    short8 pb[2][2];
#pragma unroll
    for (int g = 0; g < 2; ++g) {
      float pe[4][4];
#pragma unroll
      for (int c = 0; c < 4; ++c) {
#pragma unroll
        for (int r = 0; r < 4; ++r)
          pe[c][r] = fast_exp2(fmaf(acc[g][c][r], S2, nm[g]));
        lrun[g] += (pe[c][0] + pe[c][1]) + (pe[c][2] + pe[c][3]);
      }
#pragma unroll
      for (int r = 0; r < 4; ++r) {
        pb[g][0][r]     = (short)f2bfbits(pe[0][r]);
        pb[g][0][4 + r] = (short)f2bfbits(pe[1][r]);
        pb[g][1][r]     = (short)f2bfbits(pe[2][r]);
        pb[g][1][4 + r] = (short)f2bfbits(pe[3][r]);
      }
    }

    // ---- PV: Vt fragments direct from global (L1/L2-resident; addresses
    //      depend only on vtg -> loads hoist above the exp chain)
#pragma unroll
    for (int kc = 0; kc < 2; ++kc) {
      const int ko = kc ? ko1 : ko0;
#pragma unroll
      for (int dc = 0; dc < 4; ++dc) {
        short8 vb = *(const short8*)(vtg + (dc * 16 + lr) * 128 + ko);
        oacc[0][dc] = mfma_bf16(pb[0][kc], vb, oacc[0][dc]);
        oacc[1][dc] = mfma_bf16(pb[1][kc], vb, oacc[1][dc]);
      }
    }

    __syncthreads();   // ordered drain: staged K landed + sbuf safe to reuse
  }

  // ---- finish denominators and write
#pragma unroll
  for (int g = 0; g < 2; ++g) {
    float lsum = lrun[g];
    lsum += __shfl_xor(lsum, 16);
    lsum += __shfl_xor(lsum, 32);

    if (writeDirect) {
      float lq[4];
#pragma unroll
      for (int r = 0; r < 4; ++r) lq[r] = __shfl(lsum, lg * 4 + r);
#pragma unroll
      for (int r = 0; r < 4; ++r) {
        const float inv = 1.0f / lq[r];
        const size_t grow = (size_t)(qt * 128 + w * 32 + g * 16 + lg * 4 + r) * DIM;
#pragma unroll
        for (int dc = 0; dc < 4; ++dc) {
          const int col = dc * 16 + lr;
          const float pv = p[grow + col];
          out[grow + col] = pv + 0.1f * (oacc[g][dc][r] * inv - pv);
        }
      }
    } else {
      float* po = partO + (size_t)(qt * S + s) * 8192;
      float* pl = partL + (size_t)(qt * S + s) * 128;
#pragma unroll
      for (int r = 0; r < 4; ++r) {
        const int row = w * 32 + g * 16 + lg * 4 + r;
#pragma unroll
        for (int dc = 0; dc < 4; ++dc)
          po[row * 64 + dc * 16 + lr] = oacc[g][dc][r];
      }
      if (l < 16) pl[w * 32 + g * 16 + l] = lsum;
    }
  }
}

// ------- split-KV merge: plain sums (shared fixed m-hat per row) -------------
__global__ __launch_bounds__(256)
void reduce_kernel(const float* __restrict__ p, const float* __restrict__ partO,
                   const float* __restrict__ partL, float* __restrict__ out, int S) {
  const int t   = threadIdx.x;
  const int row = blockIdx.x * 16 + (t >> 4);
  const int c0  = (t & 15) * 4;
  const int qt  = row >> 7;
  const int rin = row & 127;

  float L = 0.f;
  float4 O = {0.f, 0.f, 0.f, 0.f};
  for (int s2 = 0; s2 < S; ++s2) {
    const size_t b = (size_t)(qt * S + s2);
    L += partL[b * 128 + rin];
    const float4 o4 = *(const float4*)&partO[b * 8192 + rin * 64 + c0];
    O.x += o4.x; O.y += o4.y; O.z += o4.z; O.w += o4.w;
  }
  const float inv = 1.0f / L;
  const float4 pv = *(const float4*)&p[(size_t)row * DIM + c0];
  float4 r;
  r.x = pv.x + 0.1f * (O.x * inv - pv.x);
  r.y = pv.y + 0.1f * (O.y * inv - pv.y);
  r.z = pv.z + 0.1f * (O.z * inv - pv.z);
  r.w = pv.w + 0.1f * (O.w * inv - pv.w);
  *(float4*)&out[(size_t)row * DIM + c0] = r;
}

// ------- fallback (R1 kernel, proven) if ws too small ------------------------
#define LDE 88
__global__ __launch_bounds__(256)
void grad_attn_fb(const float* __restrict__ p, float* __restrict__ out) {
  __shared__ __align__(16) unsigned short sKhi[BK][LDE];
  __shared__ __align__(16) unsigned short sKlo[BK][LDE];
  __shared__ __align__(16) unsigned short sVt[DIM][LDE];
  __shared__ __align__(16) unsigned short sP[4][16][LDE];
  const int t = threadIdx.x, w = t >> 6, l = t & 63, lr = l & 15, lg = l >> 4;
  const int q0 = blockIdx.x * 64 + w * 16;
  short8 qhi[2], qlo[2];
#pragma unroll
  for (int kc = 0; kc < 2; ++kc) {
    const float* qp = p + (size_t)(q0 + lr) * DIM + kc * 32 + lg * 8;
    float4 fa = *(const float4*)qp;
    float4 fb = *(const float4*)(qp + 4);
    float v[8] = {fa.x, fa.y, fa.z, fa.w, fb.x, fb.y, fb.z, fb.w};
    short8 h, lo2;
#pragma unroll
    for (int i = 0; i < 8; ++i) {
      unsigned short hb = f2bf(v[i]);
      h[i] = (short)hb;
      lo2[i] = (short)f2bf(v[i] - bf2f(hb));
    }
    qhi[kc] = h; qlo[kc] = lo2;
  }
  const f32x4 z4 = {0.f, 0.f, 0.f, 0.f};
  f32x4 oacc[4] = {z4, z4, z4, z4};
  float mrun[4] = {-1e30f, -1e30f, -1e30f, -1e30f};
  float lrun[4] = {0.f, 0.f, 0.f, 0.f};
  const int srow = (t >> 3) * 2, sc0 = (t & 7) * 8;
  const int scs = sc0 ^ (((srow >> 3) & 7) << 3);
  const float S2 = -4.0f * LOG2E;
  for (int kt = 0; kt < NT; ++kt) {
    const int kv0 = kt * BK;
    __syncthreads();
    {
      const float* s0 = p + (size_t)(kv0 + srow) * DIM + sc0;
      float4 a0 = *(const float4*)s0;
      float4 b0 = *(const float4*)(s0 + 4);
      float4 a1 = *(const float4*)(s0 + DIM);
      float4 b1 = *(const float4*)(s0 + DIM + 4);
      float v0[8] = {a0.x, a0.y, a0.z, a0.w, b0.x, b0.y, b0.z, b0.w};
      float v1[8] = {a1.x, a1.y, a1.z, a1.w, b1.x, b1.y, b1.z, b1.w};
      short8 h0, h1, l0, l1;
#pragma unroll
      for (int i = 0; i < 8; ++i) {
        unsigned short hb0 = f2bf(v0[i]);
        unsigned short hb1 = f2bf(v1[i]);
        h0[i] = (short)hb0; l0[i] = (short)f2bf(v0[i] - bf2f(hb0));
        h1[i] = (short)hb1; l1[i] = (short)f2bf(v1[i] - bf2f(hb1));
      }
      *(short8*)&sKhi[srow][scs] = h0;
      *(short8*)&sKlo[srow][scs] = l0;
      *(short8*)&sKhi[srow + 1][scs] = h1;
      *(short8*)&sKlo[srow + 1][scs] = l1;
#pragma unroll
      for (int i = 0; i < 8; ++i) {
        int d = sc0 + i;
        unsigned pk = (unsigned)(unsigned short)h0[i] |
                      (((unsigned)(unsigned short)h1[i]) << 16);
        *(unsigned*)&sVt[d][srow ^ (((d >> 3) & 7) << 3)] = pk;
      }
    }
    __syncthreads();
    f32x4 acc[4] = {z4, z4, z4, z4};
#pragma unroll
    for (int c = 0; c < 4; ++c) {
      const int krow = c * 16 + lr;
      const int swc = ((krow >> 3) & 7) << 3;
#pragma unroll
      for (int kc = 0; kc < 2; ++kc) {
        const int off = (kc * 32 + lg * 8) ^ swc;
        short8 bh = *(const short8*)&sKhi[krow][off];
        short8 bl = *(const short8*)&sKlo[krow][off];
        acc[c] = mfma_bf16(qhi[kc], bh, acc[c]);
        acc[c] = mfma_bf16(qhi[kc], bl, acc[c]);
        acc[c] = mfma_bf16(qlo[kc], bh, acc[c]);
      }
    }
    float P[4][4];
#pragma unroll
    for (int r = 0; r < 4; ++r) {
      float e0 = acc[0][r] * S2, e1 = acc[1][r] * S2;
      float e2 = acc[2][r] * S2, e3 = acc[3][r] * S2;
      float mt = fmaxf(fmaxf(e0, e1), fmaxf(e2, e3));
      mt = fmaxf(mt, __shfl_xor(mt, 1));
      mt = fmaxf(mt, __shfl_xor(mt, 2));
      mt = fmaxf(mt, __shfl_xor(mt, 4));
      mt = fmaxf(mt, __shfl_xor(mt, 8));
      const float mn = fmaxf(mrun[r], mt);
      const float sc = exp2f(mrun[r] - mn);
      mrun[r] = mn;
      float p0 = exp2f(e0 - mn), p1 = exp2f(e1 - mn);
      float p2 = exp2f(e2 - mn), p3 = exp2f(e3 - mn);
      P[0][r] = p0; P[1][r] = p1; P[2][r] = p2; P[3][r] = p3;
      float ps = (p0 + p1) + (p2 + p3);
      ps += __shfl_xor(ps, 1);
      ps += __shfl_xor(ps, 2);
      ps += __shfl_xor(ps, 4);
      ps += __shfl_xor(ps, 8);
      lrun[r] = lrun[r] * sc + ps;
#pragma unroll
      for (int dc = 0; dc < 4; ++dc) oacc[dc][r] *= sc;
    }
    {
      const int irow = lg * 4;
      const int swp = ((l >> 5) & 1) << 3;
#pragma unroll
      for (int c = 0; c < 4; ++c) {
        const int colb = (c * 16 + lr) ^ swp;
#pragma unroll
        for (int r = 0; r < 4; ++r) sP[w][irow + r][colb] = f2bf(P[c][r]);
      }
    }
#pragma unroll
    for (int kc = 0; kc < 2; ++kc) {
      const int kb = kc * 32 + lg * 8;
      short8 pa = *(const short8*)&sP[w][lr][kb ^ (((lr >> 3) & 1) << 3)];
#pragma unroll
      for (int dc = 0; dc < 4; ++dc) {
        const int d = dc * 16 + lr;
        short8 vb = *(const short8*)&sVt[d][kb ^ (((d >> 3) & 7) << 3)];
        oacc[dc] = mfma_bf16(pa, vb, oacc[dc]);
      }
    }
  }
#pragma unroll
  for (int r = 0; r < 4; ++r) {
    const float inv = 1.0f / lrun[r];
    const size_t grow = (size_t)(q0 + lg * 4 + r) * DIM;
#pragma unroll
    for (int dc = 0; dc < 4; ++dc) {
      const int col = dc * 16 + lr;
      const float pv = p[grow + col];
      out[grow + col] = pv + 0.1f * (oacc[dc][r] * inv - pv);
    }
  }
}

extern "C" void kernel_launch(void* const* d_in, const int* in_sizes, int n_in,
                              void* d_out, int out_size, void* d_ws, size_t ws_size,
                              hipStream_t stream) {
  const float* p = (const float*)d_in[0];
  float* out = (float*)d_out;
  unsigned char* ws = (unsigned char*)d_ws;
  const size_t tiles_bytes = (size_t)NT * TILE_BYTES;        // 4 MB
  const size_t mhat_bytes  = (size_t)NROWS * sizeof(float);  // 64 KB
  const size_t base = tiles_bytes + mhat_bytes;

  if (ws_size < base) {
    grad_attn_fb<<<dim3(NROWS / 64), dim3(256), 0, stream>>>(p, out);
    return;
  }
  int S = 16;
  while (S > 1) {
    size_t need = base + (size_t)NQB * S * (8192 + 128) * sizeof(float);
    if (need <= ws_size) break;
    S >>= 1;
  }
  float* mhat  = (float*)(ws + tiles_bytes);
  float* partO = (float*)(ws + base);
  float* partL = partO + (size_t)NQB * S * 8192;

  pack_kernel<<<dim3(NT), dim3(256), 0, stream>>>(p, ws, mhat);
  attn_main<<<dim3(NQB, S), dim3(256), 0, stream>>>(p, ws, mhat, out, partO, partL,
                                                    S, S == 1 ? 1 : 0);
  if (S > 1)
    reduce_kernel<<<dim3(NROWS / 16), dim3(256), 0, stream>>>(p, partO, partL, out, S);
}

// Round 18
// 94.234 us; speedup vs baseline: 1.5128x; 1.5128x over previous
//
#include <hip/hip_runtime.h>
#include <stdint.h>

#define NROWS 16384
#define DIM 64
#define BK 64
#define NT (NROWS / BK)        // 256 KV tiles
#define NQB (NROWS / 128)      // 128 q-blocks (128 q-rows each)
#define TILE_BYTES 16384       // K f16 (8K) + Vt bf16 (8K, k-permuted), swizzled
#define VT_OFF 8192
#define LOG2E 1.4426950408889634f
#define MHAT_COEF 20.0f

typedef __attribute__((ext_vector_type(8))) _Float16 f16x8;
typedef __attribute__((ext_vector_type(8))) unsigned short ushort8;
typedef __attribute__((ext_vector_type(4))) float f32x4;
typedef __attribute__((ext_vector_type(8))) __bf16 bf16x8;
typedef __attribute__((ext_vector_type(8))) short short8;

static __device__ __forceinline__ f32x4 mfma_f16(f16x8 a, f16x8 b, f32x4 c) {
  return __builtin_amdgcn_mfma_f32_16x16x32_f16(a, b, c, 0, 0, 0);
}
static __device__ __forceinline__ f32x4 mfma_bf16(short8 a, short8 b, f32x4 c) {
  return __builtin_amdgcn_mfma_f32_16x16x32_bf16(
      __builtin_bit_cast(bf16x8, a), __builtin_bit_cast(bf16x8, b), c, 0, 0, 0);
}
static __device__ __forceinline__ void gload_lds16(const void* g, void* l) {
  __builtin_amdgcn_global_load_lds(
      (const __attribute__((address_space(1))) unsigned int*)(uintptr_t)g,
      (__attribute__((address_space(3))) unsigned int*)(unsigned int)(uintptr_t)l,
      16, 0, 0);
}
static __device__ __forceinline__ float fast_exp2(float x) {
  return __builtin_amdgcn_exp2f(x);   // single v_exp_f32, hazard-scheduled
}
static __device__ __forceinline__ unsigned short f2bfbits(float x) {
  return __builtin_bit_cast(unsigned short, (__bf16)x);  // compiler emits cvt
}
// scalar bf16 helpers (pack + fallback)
static __device__ __forceinline__ unsigned short f2bf(float x) {
  unsigned u = __builtin_bit_cast(unsigned, x);
  u = (u + 0x7fffu + ((u >> 16) & 1u)) >> 16;
  return (unsigned short)u;
}
static __device__ __forceinline__ float bf2f(unsigned short b) {
  return __builtin_bit_cast(float, ((unsigned)b) << 16);
}

// ---------------- prologue: pack p -> swizzled tiles + row offsets ----------
// K half (f16): rows as-is. Vt half (bf16): vt[d][pos] = V[pi(pos)][d] with
// pi(chunk*32 + lg*8 + i) = chunk*32 + (i/4)*16 + lg*4 + (i%4)  (zero-shuffle PV).
// mhat[row] = MHAT_COEF * ||p_row|| * LOG2E  (fixed log2-domain softmax offset).
__global__ __launch_bounds__(256)
void pack_kernel(const float* __restrict__ p, unsigned char* __restrict__ tiles,
                 float* __restrict__ mhat) {
  __shared__ unsigned short sT[64][68];
  const int kt = blockIdx.x;
  const int t  = threadIdx.x;
  const int r  = t >> 2;
  const int q4 = t & 3;
  const int d0 = q4 * 16;

  const float* src = p + ((size_t)(kt * 64 + r)) * DIM + d0;
  float4 f0 = ((const float4*)src)[0];
  float4 f1 = ((const float4*)src)[1];
  float4 f2 = ((const float4*)src)[2];
  float4 f3 = ((const float4*)src)[3];
  float v[16] = {f0.x, f0.y, f0.z, f0.w, f1.x, f1.y, f1.z, f1.w,
                 f2.x, f2.y, f2.z, f2.w, f3.x, f3.y, f3.z, f3.w};
  ushort8 h0, h1, hb0, hb1;
  float sq = 0.f;
#pragma unroll
  for (int i = 0; i < 8; ++i) {
    h0[i]  = __builtin_bit_cast(unsigned short, (_Float16)v[i]);      // f16 RNE
    h1[i]  = __builtin_bit_cast(unsigned short, (_Float16)v[8 + i]);
    hb0[i] = f2bf(v[i]);                                              // bf16 RNE
    hb1[i] = f2bf(v[8 + i]);
    sq = fmaf(v[i], v[i], sq);
    sq = fmaf(v[8 + i], v[8 + i], sq);
  }
  unsigned char* tb = tiles + (size_t)kt * TILE_BYTES;
  const int swz = (r & 7) << 4;
  *(ushort8*)(tb + r * 128 + ((2 * d0) ^ swz))      = h0;
  *(ushort8*)(tb + r * 128 + ((2 * d0 + 16) ^ swz)) = h1;

  // fixed softmax offset
  sq += __shfl_xor(sq, 1);
  sq += __shfl_xor(sq, 2);
  if (q4 == 0) mhat[kt * 64 + r] = MHAT_COEF * LOG2E * sqrtf(sq);

  // Vt (bf16) via LDS transpose, pi-permuted rows
  *(ushort8*)&sT[r][d0]     = hb0;
  *(ushort8*)&sT[r][d0 + 8] = hb1;
  __syncthreads();
  const int d    = t >> 2;
  const int base = (q4 >> 1) * 32 + (q4 & 1) * 8;   // pi-gather base
  ushort8 a8, b8;
#pragma unroll
  for (int j = 0; j < 8; ++j) {
    a8[j] = sT[base + (j >> 2) * 16 + (j & 3)][d];      // pos q4*16 + j
    b8[j] = sT[base + (j >> 2) * 16 + 4 + (j & 3)][d];  // pos q4*16 + 8 + j
  }
  const int swzd = (d & 7) << 4;
  *(ushort8*)(tb + VT_OFF + d * 128 + ((2 * (q4 * 16)) ^ swzd))      = a8;
  *(ushort8*)(tb + VT_OFF + d * 128 + ((2 * (q4 * 16) + 16) ^ swzd)) = b8;
}

// ------- main flash kernel: 128 q/block, 32 q/wave, fixed-m, P in regs ------
// XCD-aware block swizzle: each XCD owns a contiguous chunk of linear block ids
// -> its KV working set (a few s-slices) stays L2-resident.
__global__ __launch_bounds__(256)
void attn_main(const float* __restrict__ p, const unsigned char* __restrict__ tiles,
               const float* __restrict__ mhat, float* __restrict__ out,
               float* __restrict__ partO, float* __restrict__ partL,
               int S, int writeDirect) {
  __shared__ __align__(16) unsigned char sbuf[2][TILE_BYTES];   // 32 KB

  const int t  = threadIdx.x;
  const int w  = t >> 6;
  const int l  = t & 63;
  const int lr = l & 15;
  const int lg = l >> 4;

  // bijective XCD swizzle (nwg = NQB*S is divisible by 8)
  const int nwg = gridDim.x * gridDim.y;
  int bid = blockIdx.y * gridDim.x + blockIdx.x;
  bid = (bid & 7) * (nwg >> 3) + (bid >> 3);
  const int qt = bid % NQB;
  const int s  = bid / NQB;

  const int ntp = NT / S;
  const int kt0 = s * ntp;
  const int swz = (lr & 7) << 4;
  const int ko0 = (lg * 16) ^ swz;
  const int ko1 = (64 + lg * 16) ^ swz;

  // Q fragments for two 16-row groups: q = qt*128 + w*32 + g*16 + lr
  f16x8 qf[2][2];
  float nm[2];
#pragma unroll
  for (int g = 0; g < 2; ++g) {
    const int grow = w * 32 + g * 16;
    const unsigned char* qtb =
        tiles + (size_t)(qt * 2 + (grow >> 6)) * TILE_BYTES;
    const int rin = (grow & 63) + lr;
    qf[g][0] = *(const f16x8*)(qtb + rin * 128 + ko0);
    qf[g][1] = *(const f16x8*)(qtb + rin * 128 + ko1);
    nm[g] = -mhat[qt * 128 + grow + lr];
  }

  const f32x4 z4 = {0.f, 0.f, 0.f, 0.f};
  f32x4 oacc[2][4] = {{z4, z4, z4, z4}, {z4, z4, z4, z4}};
  float lrun[2] = {0.f, 0.f};        // per-lane partial denominators
  const float S2 = -4.0f * LOG2E;

  auto STAGE = [&](int kt, int b) {
    const unsigned char* g = tiles + (size_t)kt * TILE_BYTES + (w * 4) * 1024 + l * 16;
    unsigned char* lb = &sbuf[b][(w * 4) * 1024];   // wave-uniform LDS base
#pragma unroll
    for (int c = 0; c < 4; ++c)
      gload_lds16(g + c * 1024, lb + c * 1024);
  };

  STAGE(kt0, 0);
  __syncthreads();

  for (int i = 0; i < ntp; ++i) {
    if (i + 1 < ntp) STAGE(kt0 + i + 1, (i + 1) & 1);

    const unsigned char* kb = &sbuf[i & 1][0];

    // ---- QK^T swapped: each kf feeds both q-groups (2 MFMA per ds_read)
    f32x4 acc[2][4] = {{z4, z4, z4, z4}, {z4, z4, z4, z4}};
#pragma unroll
    for (int c = 0; c < 4; ++c) {
      f16x8 kf0 = *(const f16x8*)(kb + (c * 16 + lr) * 128 + ko0);
      f16x8 kf1 = *(const f16x8*)(kb + (c * 16 + lr) * 128 + ko1);
      acc[0][c] = mfma_f16(kf0, qf[0][0], acc[0][c]);
      acc[1][c] = mfma_f16(kf0, qf[1][0], acc[1][c]);
      acc[0][c] = mfma_f16(kf1, qf[0][1], acc[0][c]);
      acc[1][c] = mfma_f16(kf1, qf[1][1], acc[1][c]);
    }

    // ---- fixed-m softmax per group: P = 2^(S2*dot - mhat); no shfl, no branch
    short8 pb[2][2];
#pragma unroll
    for (int g = 0; g < 2; ++g) {
      float pe[4][4];
#pragma unroll
      for (int c = 0; c < 4; ++c) {
#pragma unroll
        for (int r = 0; r < 4; ++r)
          pe[c][r] = fast_exp2(fmaf(acc[g][c][r], S2, nm[g]));
        lrun[g] += (pe[c][0] + pe[c][1]) + (pe[c][2] + pe[c][3]);
      }
#pragma unroll
      for (int r = 0; r < 4; ++r) {
        pb[g][0][r]     = (short)f2bfbits(pe[0][r]);
        pb[g][0][4 + r] = (short)f2bfbits(pe[1][r]);
        pb[g][1][r]     = (short)f2bfbits(pe[2][r]);
        pb[g][1][4 + r] = (short)f2bfbits(pe[3][r]);
      }
    }

    // ---- PV: each vb feeds both q-groups (2 MFMA per ds_read)
#pragma unroll
    for (int kc = 0; kc < 2; ++kc) {
      const int ko = kc ? ko1 : ko0;
#pragma unroll
      for (int dc = 0; dc < 4; ++dc) {
        short8 vb = *(const short8*)(kb + VT_OFF + (dc * 16 + lr) * 128 + ko);
        oacc[0][dc] = mfma_bf16(pb[0][kc], vb, oacc[0][dc]);
        oacc[1][dc] = mfma_bf16(pb[1][kc], vb, oacc[1][dc]);
      }
    }

    __syncthreads();   // ordered drain: staged tile landed + sbuf safe to reuse
  }

  // ---- finish denominators and write
#pragma unroll
  for (int g = 0; g < 2; ++g) {
    float lsum = lrun[g];
    lsum += __shfl_xor(lsum, 16);
    lsum += __shfl_xor(lsum, 32);

    if (writeDirect) {
      float lq[4];
#pragma unroll
      for (int r = 0; r < 4; ++r) lq[r] = __shfl(lsum, lg * 4 + r);
#pragma unroll
      for (int r = 0; r < 4; ++r) {
        const float inv = 1.0f / lq[r];
        const size_t grow = (size_t)(qt * 128 + w * 32 + g * 16 + lg * 4 + r) * DIM;
#pragma unroll
        for (int dc = 0; dc < 4; ++dc) {
          const int col = dc * 16 + lr;
          const float pv = p[grow + col];
          out[grow + col] = pv + 0.1f * (oacc[g][dc][r] * inv - pv);
        }
      }
    } else {
      float* po = partO + (size_t)(qt * S + s) * 8192;
      float* pl = partL + (size_t)(qt * S + s) * 128;
#pragma unroll
      for (int r = 0; r < 4; ++r) {
        const int row = w * 32 + g * 16 + lg * 4 + r;
#pragma unroll
        for (int dc = 0; dc < 4; ++dc)
          po[row * 64 + dc * 16 + lr] = oacc[g][dc][r];
      }
      if (l < 16) pl[w * 32 + g * 16 + l] = lsum;
    }
  }
}

// ------- split-KV merge: plain sums (shared fixed m-hat per row) -------------
__global__ __launch_bounds__(256)
void reduce_kernel(const float* __restrict__ p, const float* __restrict__ partO,
                   const float* __restrict__ partL, float* __restrict__ out, int S) {
  const int t   = threadIdx.x;
  const int row = blockIdx.x * 16 + (t >> 4);
  const int c0  = (t & 15) * 4;
  const int qt  = row >> 7;
  const int rin = row & 127;

  float L = 0.f;
  float4 O = {0.f, 0.f, 0.f, 0.f};
  for (int s2 = 0; s2 < S; ++s2) {
    const size_t b = (size_t)(qt * S + s2);
    L += partL[b * 128 + rin];
    const float4 o4 = *(const float4*)&partO[b * 8192 + rin * 64 + c0];
    O.x += o4.x; O.y += o4.y; O.z += o4.z; O.w += o4.w;
  }
  const float inv = 1.0f / L;
  const float4 pv = *(const float4*)&p[(size_t)row * DIM + c0];
  float4 r;
  r.x = pv.x + 0.1f * (O.x * inv - pv.x);
  r.y = pv.y + 0.1f * (O.y * inv - pv.y);
  r.z = pv.z + 0.1f * (O.z * inv - pv.z);
  r.w = pv.w + 0.1f * (O.w * inv - pv.w);
  *(float4*)&out[(size_t)row * DIM + c0] = r;
}

// ------- fallback (R1 kernel, proven) if ws too small ------------------------
#define LDE 88
__global__ __launch_bounds__(256)
void grad_attn_fb(const float* __restrict__ p, float* __restrict__ out) {
  __shared__ __align__(16) unsigned short sKhi[BK][LDE];
  __shared__ __align__(16) unsigned short sKlo[BK][LDE];
  __shared__ __align__(16) unsigned short sVt[DIM][LDE];
  __shared__ __align__(16) unsigned short sP[4][16][LDE];
  const int t = threadIdx.x, w = t >> 6, l = t & 63, lr = l & 15, lg = l >> 4;
  const int q0 = blockIdx.x * 64 + w * 16;
  short8 qhi[2], qlo[2];
#pragma unroll
  for (int kc = 0; kc < 2; ++kc) {
    const float* qp = p + (size_t)(q0 + lr) * DIM + kc * 32 + lg * 8;
    float4 fa = *(const float4*)qp;
    float4 fb = *(const float4*)(qp + 4);
    float v[8] = {fa.x, fa.y, fa.z, fa.w, fb.x, fb.y, fb.z, fb.w};
    short8 h, lo2;
#pragma unroll
    for (int i = 0; i < 8; ++i) {
      unsigned short hb = f2bf(v[i]);
      h[i] = (short)hb;
      lo2[i] = (short)f2bf(v[i] - bf2f(hb));
    }
    qhi[kc] = h; qlo[kc] = lo2;
  }
  const f32x4 z4 = {0.f, 0.f, 0.f, 0.f};
  f32x4 oacc[4] = {z4, z4, z4, z4};
  float mrun[4] = {-1e30f, -1e30f, -1e30f, -1e30f};
  float lrun[4] = {0.f, 0.f, 0.f, 0.f};
  const int srow = (t >> 3) * 2, sc0 = (t & 7) * 8;
  const int scs = sc0 ^ (((srow >> 3) & 7) << 3);
  const float S2 = -4.0f * LOG2E;
  for (int kt = 0; kt < NT; ++kt) {
    const int kv0 = kt * BK;
    __syncthreads();
    {
      const float* s0 = p + (size_t)(kv0 + srow) * DIM + sc0;
      float4 a0 = *(const float4*)s0;
      float4 b0 = *(const float4*)(s0 + 4);
      float4 a1 = *(const float4*)(s0 + DIM);
      float4 b1 = *(const float4*)(s0 + DIM + 4);
      float v0[8] = {a0.x, a0.y, a0.z, a0.w, b0.x, b0.y, b0.z, b0.w};
      float v1[8] = {a1.x, a1.y, a1.z, a1.w, b1.x, b1.y, b1.z, b1.w};
      short8 h0, h1, l0, l1;
#pragma unroll
      for (int i = 0; i < 8; ++i) {
        unsigned short hb0 = f2bf(v0[i]);
        unsigned short hb1 = f2bf(v1[i]);
        h0[i] = (short)hb0; l0[i] = (short)f2bf(v0[i] - bf2f(hb0));
        h1[i] = (short)hb1; l1[i] = (short)f2bf(v1[i] - bf2f(hb1));
      }
      *(short8*)&sKhi[srow][scs] = h0;
      *(short8*)&sKlo[srow][scs] = l0;
      *(short8*)&sKhi[srow + 1][scs] = h1;
      *(short8*)&sKlo[srow + 1][scs] = l1;
#pragma unroll
      for (int i = 0; i < 8; ++i) {
        int d = sc0 + i;
        unsigned pk = (unsigned)(unsigned short)h0[i] |
                      (((unsigned)(unsigned short)h1[i]) << 16);
        *(unsigned*)&sVt[d][srow ^ (((d >> 3) & 7) << 3)] = pk;
      }
    }
    __syncthreads();
    f32x4 acc[4] = {z4, z4, z4, z4};
#pragma unroll
    for (int c = 0; c < 4; ++c) {
      const int krow = c * 16 + lr;
      const int swc = ((krow >> 3) & 7) << 3;
#pragma unroll
      for (int kc = 0; kc < 2; ++kc) {
        const int off = (kc * 32 + lg * 8) ^ swc;
        short8 bh = *(const short8*)&sKhi[krow][off];
        short8 bl = *(const short8*)&sKlo[krow][off];
        acc[c] = mfma_bf16(qhi[kc], bh, acc[c]);
        acc[c] = mfma_bf16(qhi[kc], bl, acc[c]);
        acc[c] = mfma_bf16(qlo[kc], bh, acc[c]);
      }
    }
    float P[4][4];
#pragma unroll
    for (int r = 0; r < 4; ++r) {
      float e0 = acc[0][r] * S2, e1 = acc[1][r] * S2;
      float e2 = acc[2][r] * S2, e3 = acc[3][r] * S2;
      float mt = fmaxf(fmaxf(e0, e1), fmaxf(e2, e3));
      mt = fmaxf(mt, __shfl_xor(mt, 1));
      mt = fmaxf(mt, __shfl_xor(mt, 2));
      mt = fmaxf(mt, __shfl_xor(mt, 4));
      mt = fmaxf(mt, __shfl_xor(mt, 8));
      const float mn = fmaxf(mrun[r], mt);
      const float sc = exp2f(mrun[r] - mn);
      mrun[r] = mn;
      float p0 = exp2f(e0 - mn), p1 = exp2f(e1 - mn);
      float p2 = exp2f(e2 - mn), p3 = exp2f(e3 - mn);
      P[0][r] = p0; P[1][r] = p1; P[2][r] = p2; P[3][r] = p3;
      float ps = (p0 + p1) + (p2 + p3);
      ps += __shfl_xor(ps, 1);
      ps += __shfl_xor(ps, 2);
      ps += __shfl_xor(ps, 4);
      ps += __shfl_xor(ps, 8);
      lrun[r] = lrun[r] * sc + ps;
#pragma unroll
      for (int dc = 0; dc < 4; ++dc) oacc[dc][r] *= sc;
    }
    {
      const int irow = lg * 4;
      const int swp = ((l >> 5) & 1) << 3;
#pragma unroll
      for (int c = 0; c < 4; ++c) {
        const int colb = (c * 16 + lr) ^ swp;
#pragma unroll
        for (int r = 0; r < 4; ++r) sP[w][irow + r][colb] = f2bf(P[c][r]);
      }
    }
#pragma unroll
    for (int kc = 0; kc < 2; ++kc) {
      const int kb = kc * 32 + lg * 8;
      short8 pa = *(const short8*)&sP[w][lr][kb ^ (((lr >> 3) & 1) << 3)];
#pragma unroll
      for (int dc = 0; dc < 4; ++dc) {
        const int d = dc * 16 + lr;
        short8 vb = *(const short8*)&sVt[d][kb ^ (((d >> 3) & 7) << 3)];
        oacc[dc] = mfma_bf16(pa, vb, oacc[dc]);
      }
    }
  }
#pragma unroll
  for (int r = 0; r < 4; ++r) {
    const float inv = 1.0f / lrun[r];
    const size_t grow = (size_t)(q0 + lg * 4 + r) * DIM;
#pragma unroll
    for (int dc = 0; dc < 4; ++dc) {
      const int col = dc * 16 + lr;
      const float pv = p[grow + col];
      out[grow + col] = pv + 0.1f * (oacc[dc][r] * inv - pv);
    }
  }
}

extern "C" void kernel_launch(void* const* d_in, const int* in_sizes, int n_in,
                              void* d_out, int out_size, void* d_ws, size_t ws_size,
                              hipStream_t stream) {
  const float* p = (const float*)d_in[0];
  float* out = (float*)d_out;
  unsigned char* ws = (unsigned char*)d_ws;
  const size_t tiles_bytes = (size_t)NT * TILE_BYTES;        // 4 MB
  const size_t mhat_bytes  = (size_t)NROWS * sizeof(float);  // 64 KB
  const size_t base = tiles_bytes + mhat_bytes;

  if (ws_size < base) {
    grad_attn_fb<<<dim3(NROWS / 64), dim3(256), 0, stream>>>(p, out);
    return;
  }
  int S = 8;
  while (S > 1) {
    size_t need = base + (size_t)NQB * S * (8192 + 128) * sizeof(float);
    if (need <= ws_size) break;
    S >>= 1;
  }
  float* mhat  = (float*)(ws + tiles_bytes);
  float* partO = (float*)(ws + base);
  float* partL = partO + (size_t)NQB * S * 8192;

  pack_kernel<<<dim3(NT), dim3(256), 0, stream>>>(p, ws, mhat);
  attn_main<<<dim3(NQB, S), dim3(256), 0, stream>>>(p, ws, mhat, out, partO, partL,
                                                    S, S == 1 ? 1 : 0);
  if (S > 1)
    reduce_kernel<<<dim3(NROWS / 16), dim3(256), 0, stream>>>(p, partO, partL, out, S);
}

// Round 19
// 90.576 us; speedup vs baseline: 1.5739x; 1.0404x over previous
//
#include <hip/hip_runtime.h>
#include <stdint.h>

#define NROWS 16384
#define DIM 64
#define BK 64
#define NT (NROWS / BK)        // 256 KV tiles
#define NQB2 (NROWS / 256)     // 64 q-blocks (256 q-rows each, 8 waves)
#define TILE_BYTES 16384       // K f16 (8K) + Vt bf16 (8K, k-permuted), swizzled
#define VT_OFF 8192
#define LOG2E 1.4426950408889634f
#define MHAT_COEF 20.0f

typedef __attribute__((ext_vector_type(8))) _Float16 f16x8;
typedef __attribute__((ext_vector_type(8))) unsigned short ushort8;
typedef __attribute__((ext_vector_type(4))) float f32x4;
typedef __attribute__((ext_vector_type(8))) __bf16 bf16x8;
typedef __attribute__((ext_vector_type(8))) short short8;

static __device__ __forceinline__ f32x4 mfma_f16(f16x8 a, f16x8 b, f32x4 c) {
  return __builtin_amdgcn_mfma_f32_16x16x32_f16(a, b, c, 0, 0, 0);
}
static __device__ __forceinline__ f32x4 mfma_bf16(short8 a, short8 b, f32x4 c) {
  return __builtin_amdgcn_mfma_f32_16x16x32_bf16(
      __builtin_bit_cast(bf16x8, a), __builtin_bit_cast(bf16x8, b), c, 0, 0, 0);
}
static __device__ __forceinline__ void gload_lds16(const void* g, void* l) {
  __builtin_amdgcn_global_load_lds(
      (const __attribute__((address_space(1))) unsigned int*)(uintptr_t)g,
      (__attribute__((address_space(3))) unsigned int*)(unsigned int)(uintptr_t)l,
      16, 0, 0);
}
static __device__ __forceinline__ float fast_exp2(float x) {
  return __builtin_amdgcn_exp2f(x);   // single v_exp_f32, hazard-scheduled
}
static __device__ __forceinline__ unsigned short f2bfbits(float x) {
  return __builtin_bit_cast(unsigned short, (__bf16)x);  // compiler emits cvt
}
// scalar bf16 helpers (pack + fallback)
static __device__ __forceinline__ unsigned short f2bf(float x) {
  unsigned u = __builtin_bit_cast(unsigned, x);
  u = (u + 0x7fffu + ((u >> 16) & 1u)) >> 16;
  return (unsigned short)u;
}
static __device__ __forceinline__ float bf2f(unsigned short b) {
  return __builtin_bit_cast(float, ((unsigned)b) << 16);
}

// ---------------- prologue: pack p -> swizzled tiles + row offsets ----------
// K half (f16): rows as-is. Vt half (bf16): vt[d][pos] = V[pi(pos)][d] with
// pi(chunk*32 + lg*8 + i) = chunk*32 + (i/4)*16 + lg*4 + (i%4)  (zero-shuffle PV).
// mhat[row] = MHAT_COEF * ||p_row|| * LOG2E  (fixed log2-domain softmax offset).
__global__ __launch_bounds__(256)
void pack_kernel(const float* __restrict__ p, unsigned char* __restrict__ tiles,
                 float* __restrict__ mhat) {
  __shared__ unsigned short sT[64][68];
  const int kt = blockIdx.x;
  const int t  = threadIdx.x;
  const int r  = t >> 2;
  const int q4 = t & 3;
  const int d0 = q4 * 16;

  const float* src = p + ((size_t)(kt * 64 + r)) * DIM + d0;
  float4 f0 = ((const float4*)src)[0];
  float4 f1 = ((const float4*)src)[1];
  float4 f2 = ((const float4*)src)[2];
  float4 f3 = ((const float4*)src)[3];
  float v[16] = {f0.x, f0.y, f0.z, f0.w, f1.x, f1.y, f1.z, f1.w,
                 f2.x, f2.y, f2.z, f2.w, f3.x, f3.y, f3.z, f3.w};
  ushort8 h0, h1, hb0, hb1;
  float sq = 0.f;
#pragma unroll
  for (int i = 0; i < 8; ++i) {
    h0[i]  = __builtin_bit_cast(unsigned short, (_Float16)v[i]);      // f16 RNE
    h1[i]  = __builtin_bit_cast(unsigned short, (_Float16)v[8 + i]);
    hb0[i] = f2bf(v[i]);                                              // bf16 RNE
    hb1[i] = f2bf(v[8 + i]);
    sq = fmaf(v[i], v[i], sq);
    sq = fmaf(v[8 + i], v[8 + i], sq);
  }
  unsigned char* tb = tiles + (size_t)kt * TILE_BYTES;
  const int swz = (r & 7) << 4;
  *(ushort8*)(tb + r * 128 + ((2 * d0) ^ swz))      = h0;
  *(ushort8*)(tb + r * 128 + ((2 * d0 + 16) ^ swz)) = h1;

  // fixed softmax offset
  sq += __shfl_xor(sq, 1);
  sq += __shfl_xor(sq, 2);
  if (q4 == 0) mhat[kt * 64 + r] = MHAT_COEF * LOG2E * sqrtf(sq);

  // Vt (bf16) via LDS transpose, pi-permuted rows
  *(ushort8*)&sT[r][d0]     = hb0;
  *(ushort8*)&sT[r][d0 + 8] = hb1;
  __syncthreads();
  const int d    = t >> 2;
  const int base = (q4 >> 1) * 32 + (q4 & 1) * 8;   // pi-gather base
  ushort8 a8, b8;
#pragma unroll
  for (int j = 0; j < 8; ++j) {
    a8[j] = sT[base + (j >> 2) * 16 + (j & 3)][d];      // pos q4*16 + j
    b8[j] = sT[base + (j >> 2) * 16 + 4 + (j & 3)][d];  // pos q4*16 + 8 + j
  }
  const int swzd = (d & 7) << 4;
  *(ushort8*)(tb + VT_OFF + d * 128 + ((2 * (q4 * 16)) ^ swzd))      = a8;
  *(ushort8*)(tb + VT_OFF + d * 128 + ((2 * (q4 * 16) + 16) ^ swzd)) = b8;
}

// ------- main flash kernel: 256 q/block (8 waves), shared KV tile -----------
__global__ __launch_bounds__(512)
void attn_main(const float* __restrict__ p, const unsigned char* __restrict__ tiles,
               const float* __restrict__ mhat, float* __restrict__ out,
               float* __restrict__ partO, float* __restrict__ partL,
               int S, int writeDirect) {
  __shared__ __align__(16) unsigned char sbuf[2][TILE_BYTES];   // 32 KB

  const int t  = threadIdx.x;
  const int w  = t >> 6;      // 0..7
  const int l  = t & 63;
  const int lr = l & 15;
  const int lg = l >> 4;

  // bijective XCD swizzle (nwg = NQB2*S is divisible by 8)
  const int nwg = gridDim.x * gridDim.y;
  int bid = blockIdx.y * gridDim.x + blockIdx.x;
  bid = (bid & 7) * (nwg >> 3) + (bid >> 3);
  const int qt = bid % NQB2;
  const int s  = bid / NQB2;

  const int ntp = NT / S;
  const int kt0 = s * ntp;
  const int swz = (lr & 7) << 4;
  const int ko0 = (lg * 16) ^ swz;
  const int ko1 = (64 + lg * 16) ^ swz;

  // Q fragments for two 16-row groups: q = qt*256 + w*32 + g*16 + lr
  f16x8 qf[2][2];
  float nm[2];
#pragma unroll
  for (int g = 0; g < 2; ++g) {
    const int grow = w * 32 + g * 16;   // 0..240
    const unsigned char* qtb =
        tiles + (size_t)(qt * 4 + (grow >> 6)) * TILE_BYTES;
    const int rin = (grow & 63) + lr;
    qf[g][0] = *(const f16x8*)(qtb + rin * 128 + ko0);
    qf[g][1] = *(const f16x8*)(qtb + rin * 128 + ko1);
    nm[g] = -mhat[qt * 256 + grow + lr];
  }

  const f32x4 z4 = {0.f, 0.f, 0.f, 0.f};
  f32x4 oacc[2][4] = {{z4, z4, z4, z4}, {z4, z4, z4, z4}};
  float lrun[2] = {0.f, 0.f};        // per-lane partial denominators
  const float S2 = -4.0f * LOG2E;

  // stage full tile (16KB): 2KB per wave (8 waves)
  auto STAGE = [&](int kt, int b) {
    const unsigned char* g = tiles + (size_t)kt * TILE_BYTES + w * 2048 + l * 16;
    unsigned char* lb = &sbuf[b][w * 2048];   // wave-uniform LDS base
    gload_lds16(g, lb);
    gload_lds16(g + 1024, lb + 1024);
  };

  STAGE(kt0, 0);
  __syncthreads();

  for (int i = 0; i < ntp; ++i) {
    if (i + 1 < ntp) STAGE(kt0 + i + 1, (i + 1) & 1);

    const unsigned char* kb = &sbuf[i & 1][0];

    // ---- QK^T swapped: each kf feeds both q-groups (2 MFMA per ds_read)
    f32x4 acc[2][4] = {{z4, z4, z4, z4}, {z4, z4, z4, z4}};
#pragma unroll
    for (int c = 0; c < 4; ++c) {
      f16x8 kf0 = *(const f16x8*)(kb + (c * 16 + lr) * 128 + ko0);
      f16x8 kf1 = *(const f16x8*)(kb + (c * 16 + lr) * 128 + ko1);
      acc[0][c] = mfma_f16(kf0, qf[0][0], acc[0][c]);
      acc[1][c] = mfma_f16(kf0, qf[1][0], acc[1][c]);
      acc[0][c] = mfma_f16(kf1, qf[0][1], acc[0][c]);
      acc[1][c] = mfma_f16(kf1, qf[1][1], acc[1][c]);
    }

    // ---- fixed-m softmax per group: P = 2^(S2*dot - mhat); no shfl, no branch
    short8 pb[2][2];
#pragma unroll
    for (int g = 0; g < 2; ++g) {
      float pe[4][4];
#pragma unroll
      for (int c = 0; c < 4; ++c) {
#pragma unroll
        for (int r = 0; r < 4; ++r)
          pe[c][r] = fast_exp2(fmaf(acc[g][c][r], S2, nm[g]));
        lrun[g] += (pe[c][0] + pe[c][1]) + (pe[c][2] + pe[c][3]);
      }
#pragma unroll
      for (int r = 0; r < 4; ++r) {
        pb[g][0][r]     = (short)f2bfbits(pe[0][r]);
        pb[g][0][4 + r] = (short)f2bfbits(pe[1][r]);
        pb[g][1][r]     = (short)f2bfbits(pe[2][r]);
        pb[g][1][4 + r] = (short)f2bfbits(pe[3][r]);
      }
    }

    // ---- PV: each vb feeds both q-groups (2 MFMA per ds_read)
#pragma unroll
    for (int kc = 0; kc < 2; ++kc) {
      const int ko = kc ? ko1 : ko0;
#pragma unroll
      for (int dc = 0; dc < 4; ++dc) {
        short8 vb = *(const short8*)(kb + VT_OFF + (dc * 16 + lr) * 128 + ko);
        oacc[0][dc] = mfma_bf16(pb[0][kc], vb, oacc[0][dc]);
        oacc[1][dc] = mfma_bf16(pb[1][kc], vb, oacc[1][dc]);
      }
    }

    __syncthreads();   // ordered drain: staged tile landed + sbuf safe to reuse
  }

  // ---- finish denominators and write
#pragma unroll
  for (int g = 0; g < 2; ++g) {
    float lsum = lrun[g];
    lsum += __shfl_xor(lsum, 16);
    lsum += __shfl_xor(lsum, 32);

    if (writeDirect) {
      float lq[4];
#pragma unroll
      for (int r = 0; r < 4; ++r) lq[r] = __shfl(lsum, lg * 4 + r);
#pragma unroll
      for (int r = 0; r < 4; ++r) {
        const float inv = 1.0f / lq[r];
        const size_t grow = (size_t)(qt * 256 + w * 32 + g * 16 + lg * 4 + r) * DIM;
#pragma unroll
        for (int dc = 0; dc < 4; ++dc) {
          const int col = dc * 16 + lr;
          const float pv = p[grow + col];
          out[grow + col] = pv + 0.1f * (oacc[g][dc][r] * inv - pv);
        }
      }
    } else {
      float* po = partO + (size_t)(qt * S + s) * 16384;
      float* pl = partL + (size_t)(qt * S + s) * 256;
#pragma unroll
      for (int r = 0; r < 4; ++r) {
        const int row = w * 32 + g * 16 + lg * 4 + r;
#pragma unroll
        for (int dc = 0; dc < 4; ++dc)
          po[row * 64 + dc * 16 + lr] = oacc[g][dc][r];
      }
      if (l < 16) pl[w * 32 + g * 16 + l] = lsum;
    }
  }
}

// ------- split-KV merge: plain sums (shared fixed m-hat per row) -------------
__global__ __launch_bounds__(256)
void reduce_kernel(const float* __restrict__ p, const float* __restrict__ partO,
                   const float* __restrict__ partL, float* __restrict__ out, int S) {
  const int t   = threadIdx.x;
  const int row = blockIdx.x * 16 + (t >> 4);
  const int c0  = (t & 15) * 4;
  const int qt  = row >> 8;
  const int rin = row & 255;

  float L = 0.f;
  float4 O = {0.f, 0.f, 0.f, 0.f};
  for (int s2 = 0; s2 < S; ++s2) {
    const size_t b = (size_t)(qt * S + s2);
    L += partL[b * 256 + rin];
    const float4 o4 = *(const float4*)&partO[b * 16384 + rin * 64 + c0];
    O.x += o4.x; O.y += o4.y; O.z += o4.z; O.w += o4.w;
  }
  const float inv = 1.0f / L;
  const float4 pv = *(const float4*)&p[(size_t)row * DIM + c0];
  float4 r;
  r.x = pv.x + 0.1f * (O.x * inv - pv.x);
  r.y = pv.y + 0.1f * (O.y * inv - pv.y);
  r.z = pv.z + 0.1f * (O.z * inv - pv.z);
  r.w = pv.w + 0.1f * (O.w * inv - pv.w);
  *(float4*)&out[(size_t)row * DIM + c0] = r;
}

// ------- fallback (R1 kernel, proven) if ws too small ------------------------
#define LDE 88
__global__ __launch_bounds__(256)
void grad_attn_fb(const float* __restrict__ p, float* __restrict__ out) {
  __shared__ __align__(16) unsigned short sKhi[BK][LDE];
  __shared__ __align__(16) unsigned short sKlo[BK][LDE];
  __shared__ __align__(16) unsigned short sVt[DIM][LDE];
  __shared__ __align__(16) unsigned short sP[4][16][LDE];
  const int t = threadIdx.x, w = t >> 6, l = t & 63, lr = l & 15, lg = l >> 4;
  const int q0 = blockIdx.x * 64 + w * 16;
  short8 qhi[2], qlo[2];
#pragma unroll
  for (int kc = 0; kc < 2; ++kc) {
    const float* qp = p + (size_t)(q0 + lr) * DIM + kc * 32 + lg * 8;
    float4 fa = *(const float4*)qp;
    float4 fb = *(const float4*)(qp + 4);
    float v[8] = {fa.x, fa.y, fa.z, fa.w, fb.x, fb.y, fb.z, fb.w};
    short8 h, lo2;
#pragma unroll
    for (int i = 0; i < 8; ++i) {
      unsigned short hb = f2bf(v[i]);
      h[i] = (short)hb;
      lo2[i] = (short)f2bf(v[i] - bf2f(hb));
    }
    qhi[kc] = h; qlo[kc] = lo2;
  }
  const f32x4 z4 = {0.f, 0.f, 0.f, 0.f};
  f32x4 oacc[4] = {z4, z4, z4, z4};
  float mrun[4] = {-1e30f, -1e30f, -1e30f, -1e30f};
  float lrun[4] = {0.f, 0.f, 0.f, 0.f};
  const int srow = (t >> 3) * 2, sc0 = (t & 7) * 8;
  const int scs = sc0 ^ (((srow >> 3) & 7) << 3);
  const float S2 = -4.0f * LOG2E;
  for (int kt = 0; kt < NT; ++kt) {
    const int kv0 = kt * BK;
    __syncthreads();
    {
      const float* s0 = p + (size_t)(kv0 + srow) * DIM + sc0;
      float4 a0 = *(const float4*)s0;
      float4 b0 = *(const float4*)(s0 + 4);
      float4 a1 = *(const float4*)(s0 + DIM);
      float4 b1 = *(const float4*)(s0 + DIM + 4);
      float v0[8] = {a0.x, a0.y, a0.z, a0.w, b0.x, b0.y, b0.z, b0.w};
      float v1[8] = {a1.x, a1.y, a1.z, a1.w, b1.x, b1.y, b1.z, b1.w};
      short8 h0, h1, l0, l1;
#pragma unroll
      for (int i = 0; i < 8; ++i) {
        unsigned short hb0 = f2bf(v0[i]);
        unsigned short hb1 = f2bf(v1[i]);
        h0[i] = (short)hb0; l0[i] = (short)f2bf(v0[i] - bf2f(hb0));
        h1[i] = (short)hb1; l1[i] = (short)f2bf(v1[i] - bf2f(hb1));
      }
      *(short8*)&sKhi[srow][scs] = h0;
      *(short8*)&sKlo[srow][scs] = l0;
      *(short8*)&sKhi[srow + 1][scs] = h1;
      *(short8*)&sKlo[srow + 1][scs] = l1;
#pragma unroll
      for (int i = 0; i < 8; ++i) {
        int d = sc0 + i;
        unsigned pk = (unsigned)(unsigned short)h0[i] |
                      (((unsigned)(unsigned short)h1[i]) << 16);
        *(unsigned*)&sVt[d][srow ^ (((d >> 3) & 7) << 3)] = pk;
      }
    }
    __syncthreads();
    f32x4 acc[4] = {z4, z4, z4, z4};
#pragma unroll
    for (int c = 0; c < 4; ++c) {
      const int krow = c * 16 + lr;
      const int swc = ((krow >> 3) & 7) << 3;
#pragma unroll
      for (int kc = 0; kc < 2; ++kc) {
        const int off = (kc * 32 + lg * 8) ^ swc;
        short8 bh = *(const short8*)&sKhi[krow][off];
        short8 bl = *(const short8*)&sKlo[krow][off];
        acc[c] = mfma_bf16(qhi[kc], bh, acc[c]);
        acc[c] = mfma_bf16(qhi[kc], bl, acc[c]);
        acc[c] = mfma_bf16(qlo[kc], bh, acc[c]);
      }
    }
    float P[4][4];
#pragma unroll
    for (int r = 0; r < 4; ++r) {
      float e0 = acc[0][r] * S2, e1 = acc[1][r] * S2;
      float e2 = acc[2][r] * S2, e3 = acc[3][r] * S2;
      float mt = fmaxf(fmaxf(e0, e1), fmaxf(e2, e3));
      mt = fmaxf(mt, __shfl_xor(mt, 1));
      mt = fmaxf(mt, __shfl_xor(mt, 2));
      mt = fmaxf(mt, __shfl_xor(mt, 4));
      mt = fmaxf(mt, __shfl_xor(mt, 8));
      const float mn = fmaxf(mrun[r], mt);
      const float sc = exp2f(mrun[r] - mn);
      mrun[r] = mn;
      float p0 = exp2f(e0 - mn), p1 = exp2f(e1 - mn);
      float p2 = exp2f(e2 - mn), p3 = exp2f(e3 - mn);
      P[0][r] = p0; P[1][r] = p1; P[2][r] = p2; P[3][r] = p3;
      float ps = (p0 + p1) + (p2 + p3);
      ps += __shfl_xor(ps, 1);
      ps += __shfl_xor(ps, 2);
      ps += __shfl_xor(ps, 4);
      ps += __shfl_xor(ps, 8);
      lrun[r] = lrun[r] * sc + ps;
#pragma unroll
      for (int dc = 0; dc < 4; ++dc) oacc[dc][r] *= sc;
    }
    {
      const int irow = lg * 4;
      const int swp = ((l >> 5) & 1) << 3;
#pragma unroll
      for (int c = 0; c < 4; ++c) {
        const int colb = (c * 16 + lr) ^ swp;
#pragma unroll
        for (int r = 0; r < 4; ++r) sP[w][irow + r][colb] = f2bf(P[c][r]);
      }
    }
#pragma unroll
    for (int kc = 0; kc < 2; ++kc) {
      const int kb = kc * 32 + lg * 8;
      short8 pa = *(const short8*)&sP[w][lr][kb ^ (((lr >> 3) & 1) << 3)];
#pragma unroll
      for (int dc = 0; dc < 4; ++dc) {
        const int d = dc * 16 + lr;
        short8 vb = *(const short8*)&sVt[d][kb ^ (((d >> 3) & 7) << 3)];
        oacc[dc] = mfma_bf16(pa, vb, oacc[dc]);
      }
    }
  }
#pragma unroll
  for (int r = 0; r < 4; ++r) {
    const float inv = 1.0f / lrun[r];
    const size_t grow = (size_t)(q0 + lg * 4 + r) * DIM;
#pragma unroll
    for (int dc = 0; dc < 4; ++dc) {
      const int col = dc * 16 + lr;
      const float pv = p[grow + col];
      out[grow + col] = pv + 0.1f * (oacc[dc][r] * inv - pv);
    }
  }
}

extern "C" void kernel_launch(void* const* d_in, const int* in_sizes, int n_in,
                              void* d_out, int out_size, void* d_ws, size_t ws_size,
                              hipStream_t stream) {
  const float* p = (const float*)d_in[0];
  float* out = (float*)d_out;
  unsigned char* ws = (unsigned char*)d_ws;
  const size_t tiles_bytes = (size_t)NT * TILE_BYTES;        // 4 MB
  const size_t mhat_bytes  = (size_t)NROWS * sizeof(float);  // 64 KB
  const size_t base = tiles_bytes + mhat_bytes;

  if (ws_size < base) {
    grad_attn_fb<<<dim3(NROWS / 64), dim3(256), 0, stream>>>(p, out);
    return;
  }
  int S = 16;
  while (S > 1) {
    size_t need = base + (size_t)NQB2 * S * (16384 + 256) * sizeof(float);
    if (need <= ws_size) break;
    S >>= 1;
  }
  float* mhat  = (float*)(ws + tiles_bytes);
  float* partO = (float*)(ws + base);
  float* partL = partO + (size_t)NQB2 * S * 16384;

  pack_kernel<<<dim3(NT), dim3(256), 0, stream>>>(p, ws, mhat);
  attn_main<<<dim3(NQB2, S), dim3(512), 0, stream>>>(p, ws, mhat, out, partO, partL,
                                                     S, S == 1 ? 1 : 0);
  if (S > 1)
    reduce_kernel<<<dim3(NROWS / 16), dim3(256), 0, stream>>>(p, partO, partL, out, S);
}